// Round 7
// baseline (565.298 us; speedup 1.0000x reference)
//
#include <hip/hip_runtime.h>
#include <math.h>

// Problem constants
#define NVEC  32768          // B*L = 64*512
#define DDIM  512            // CODE_DIM
#define KCB   4              // NUM_CODEBOOKS
#define SCB   1024           // CODEBOOK_SIZE
#define SUBD  128            // SUB_DIM

#define IDX_COUNT (NVEC * KCB)            // 131072
#define ZQ_COUNT  (NVEC * DDIM)           // 16777216
#define OFF_ZQ_ST  IDX_COUNT
#define OFF_ZQ_ALL (IDX_COUNT + ZQ_COUNT)
#define OFF_SCAL   (IDX_COUNT + 2 * ZQ_COUNT)

// Scratch layout inside the z_q_all output region (all consumed before
// k_gather overwrites it; d_ws unused):
//   counts : int  [4096]               at zq_all + 0       (floats)
//   c2s    : f32  [4096] (scaled 2^20) at zq_all + 4096
//   c2np   : f32  [4096] (np-exact)    at zq_all + 8192
//   cb16   : fp16 [4096][128] (x1024)  at zq_all + 12288   (1 MB, ends 274432)
//   cand   : u16  [131072][8]          at zq_all + 274432  (2 MB, ends 798720)
//   ctrs   : int  [2]                  at zq_all + 800000

typedef _Float16 v2h __attribute__((ext_vector_type(2)));
typedef _Float16 f16x8 __attribute__((ext_vector_type(8)));
typedef float f32x16 __attribute__((ext_vector_type(16)));
union U32H2 { unsigned int u; v2h h; };

// Strict (non-contractable) f32 ops replicating numpy's rounding exactly.
__device__ __forceinline__ float fmul(float a, float b) { return __fmul_rn(a, b); }
__device__ __forceinline__ float fadd(float a, float b) { return __fadd_rn(a, b); }
__device__ __forceinline__ float fsub(float a, float b) { return __fsub_rn(a, b); }

// numpy pairwise_sum for n=128 (scalar 8-accumulator path); elements are
// individually-rounded f32 products. Validated (PASS since round 4).
__device__ __forceinline__ float np_dot128(const float* __restrict__ u,
                                           const float* __restrict__ v) {
  float r[8];
#pragma unroll
  for (int j = 0; j < 8; ++j) r[j] = fmul(u[j], v[j]);
#pragma unroll
  for (int i = 8; i < 128; i += 8) {
#pragma unroll
    for (int j = 0; j < 8; ++j) r[j] = fadd(r[j], fmul(u[i + j], v[i + j]));
  }
  return fadd(fadd(fadd(r[0], r[1]), fadd(r[2], r[3])),
              fadd(fadd(r[4], r[5]), fadd(r[6], r[7])));
}

__device__ __forceinline__ int imin(int a, int b) { return a < b ? a : b; }
__device__ __forceinline__ int imax(int a, int b) { return a > b ? a : b; }

// Branch-free sorted insert of x into ascending (k0<=k1<=k2<=k3): 7 VALU ops.
__device__ __forceinline__ void ins4(int& k0, int& k1, int& k2, int& k3, int x) {
  int a = imax(k0, x); k0 = imin(k0, x);
  int b = imax(k1, a); k1 = imin(k1, a);
  int c = imax(k2, b); k2 = imin(k2, b);
  k3 = imin(k3, c);
}

// ---------------------------------------------------------------------------
// k_prep: fused convert + c2np + all zero-init. Grid 64x256.
// ---------------------------------------------------------------------------
__global__ __launch_bounds__(256) void k_prep(
    const float* __restrict__ cb, unsigned int* __restrict__ cb16,
    float* __restrict__ c2s, float* __restrict__ c2np,
    int* __restrict__ counts, float* __restrict__ scal,
    int* __restrict__ ctrs) {
  const int gt = blockIdx.x * 256 + threadIdx.x;   // 0..16383
  if (gt < KCB * SCB) counts[gt] = 0;
  if (gt < 3) scal[gt] = 0.0f;
  if (gt < 2) ctrs[gt] = 0;
  if (gt < KCB * SCB) {
    const float* row = cb + (size_t)gt * SUBD;
    c2np[gt] = np_dot128(row, row);
  }
  const int wave = blockIdx.x * 4 + (threadIdx.x >> 6);
  const int lane = threadIdx.x & 63;
  for (int i = 0; i < 16; ++i) {
    const int code = wave * 16 + i;   // 0..4095
    const float2 v = ((const float2*)(cb + (size_t)code * SUBD))[lane];
    float tot = fmaf(v.x, v.x, v.y * v.y);
#pragma unroll
    for (int off = 32; off > 0; off >>= 1) tot += __shfl_down(tot, off, 64);
    v2h h; h.x = (_Float16)(v.x * 1024.0f); h.y = (_Float16)(v.y * 1024.0f);
    U32H2 t; t.h = h;
    cb16[(size_t)code * 64 + lane] = t.u;
    if (lane == 0) c2s[code] = tot * 1048576.0f;  // * 2^20
  }
}

// ---------------------------------------------------------------------------
// k_scan: byte-identical to the PASSING round-5 kernel (MFMA + packed-key
// top-4 + global_load_lds width=16 async staging).
// ---------------------------------------------------------------------------
#define SCORE(ACC, STOFF, K0, K1, K2, K3)                                    \
  {                                                                          \
    _Pragma("unroll")                                                        \
    for (int g = 0; g < 4; ++g) {                                            \
      const float4 cv = *(const float4*)(c2b + (STOFF) + hi * 4 + g * 8);    \
      const float ca[4] = {cv.x, cv.y, cv.z, cv.w};                          \
      _Pragma("unroll")                                                      \
      for (int r = 0; r < 4; ++r) {                                          \
        const float sc = fmaf(-2048.0f, (ACC)[g * 4 + r], ca[r]);            \
        const int key = ((int)sc << 10) | (tb + (STOFF) + hi * 4 + g * 8 + r); \
        ins4(K0, K1, K2, K3, key);                                           \
      }                                                                      \
    }                                                                        \
  }

// One 16 KB tile: per wave w, chunk p covers uint4 slots [p*256+w*64,
// p*256+w*64+64). Lane l supplies the 16B at global index
// (p*16 + rbase)*16 + ss (pre-swizzled source).
__device__ __forceinline__ void stage_tile(const uint4* __restrict__ gsrc,
                                           unsigned int* lds_u32,
                                           int w, int rbase, int ss) {
#pragma unroll
  for (int p = 0; p < 4; ++p) {
    const uint4* src = gsrc + (size_t)((p * 16 + rbase) * 16 + ss);
    unsigned int* dst = lds_u32 + (p * 256 + w * 64) * 4;  // wave-uniform
    __builtin_amdgcn_global_load_lds(
        (const __attribute__((address_space(1))) unsigned int*)src,
        (__attribute__((address_space(3))) unsigned int*)dst, 16, 0, 0);
  }
}

__global__ __launch_bounds__(256) void k_scan(
    const float* __restrict__ z_e, const unsigned int* __restrict__ cb16,
    const float* __restrict__ c2s, unsigned short* __restrict__ cand) {
  const int tid = threadIdx.x;
  const int lane = tid & 63;
  const int w = tid >> 6;
  const int hi = lane >> 5;          // row-half of the lane pair
  const int ml = lane & 31;          // n-column within the wave tile
  const int k = blockIdx.y;
  const int n = blockIdx.x * 128 + w * 32 + ml;

  __shared__ __align__(16) unsigned int ctile[2][4096];  // 2 x 16 KB (64 codes)

  const uint4* gk = (const uint4*)cb16 + (size_t)k * SCB * 16;
  const float* c2k = c2s + k * SCB;
  const int rbase = tid >> 4;                 // staging row low bits
  const int ss = (tid & 15) ^ rbase;          // pre-swizzled source slot

  // B fragments: xf[ks][j] = f16(x[n][ks*16 + hi*8 + j])  (RTNE, unscaled)
  f16x8 xf[8];
  {
    const float* xp = z_e + (size_t)n * DDIM + k * SUBD + hi * 8;
#pragma unroll
    for (int ks = 0; ks < 8; ++ks) {
      const float4 a = *(const float4*)(xp + ks * 16);
      const float4 b = *(const float4*)(xp + ks * 16 + 4);
      f16x8 h;
      h[0] = (_Float16)a.x; h[1] = (_Float16)a.y;
      h[2] = (_Float16)a.z; h[3] = (_Float16)a.w;
      h[4] = (_Float16)b.x; h[5] = (_Float16)b.y;
      h[6] = (_Float16)b.z; h[7] = (_Float16)b.w;
      xf[ks] = h;
    }
  }

  // Stage tile 0 (async), then barrier (drains vmcnt).
  stage_tile(gk, ctile[0], w, rbase, ss);
  __syncthreads();

  int kA0 = 0x7FFFFFFF, kA1 = 0x7FFFFFFF, kA2 = 0x7FFFFFFF, kA3 = 0x7FFFFFFF;
  int kB0 = 0x7FFFFFFF, kB1 = 0x7FFFFFFF, kB2 = 0x7FFFFFFF, kB3 = 0x7FFFFFFF;

  for (int tile = 0; tile < 16; ++tile) {
    // Async-stage next tile into the other buffer; in flight during compute,
    // drained by the vmcnt(0) the compiler emits before the end-of-loop
    // barrier.
    if (tile < 15)
      stage_tile(gk + (size_t)(tile + 1) * 1024, ctile[(tile + 1) & 1],
                 w, rbase, ss);

    const unsigned char* bufb = (const unsigned char*)ctile[tile & 1];
    f32x16 acc0, acc1;
#pragma unroll
    for (int z = 0; z < 16; ++z) { acc0[z] = 0.0f; acc1[z] = 0.0f; }

    // Two independent 32-code MFMA chains. A-frag: row = stile*32 + ml,
    // logical 16B slot = ks*2 + hi, phys slot = slot ^ (lane&15).
#pragma unroll
    for (int ks = 0; ks < 8; ++ks) {
      const int phys = (((ks * 2 + hi) ^ (lane & 15)) << 4);
      const f16x8 a0 = *(const f16x8*)(bufb + ml * 256 + phys);
      const f16x8 a1 = *(const f16x8*)(bufb + (ml + 32) * 256 + phys);
      acc0 = __builtin_amdgcn_mfma_f32_32x32x16_f16(a0, xf[ks], acc0, 0, 0, 0);
      acc1 = __builtin_amdgcn_mfma_f32_32x32x16_f16(a1, xf[ks], acc1, 0, 0, 0);
    }

    // Scores: acc reg -> code row = (reg&3) + 8*(reg>>2) + 4*hi (m74/m101).
    const int tb = tile * 64;
    const float* c2b = c2k + tb;
    SCORE(acc0, 0, kA0, kA1, kA2, kA3)
    SCORE(acc1, 32, kB0, kB1, kB2, kB3)

    __syncthreads();
  }

  // Merge set B into set A -> top-4 of this lane's 512-code partition.
  ins4(kA0, kA1, kA2, kA3, kB0);
  ins4(kA0, kA1, kA2, kA3, kB1);
  ins4(kA0, kA1, kA2, kA3, kB2);
  ins4(kA0, kA1, kA2, kA3, kB3);

  const unsigned long long pk =
      (unsigned long long)(unsigned short)(kA0 & 1023) |
      ((unsigned long long)(unsigned short)(kA1 & 1023) << 16) |
      ((unsigned long long)(unsigned short)(kA2 & 1023) << 32) |
      ((unsigned long long)(unsigned short)(kA3 & 1023) << 48);
  *(unsigned long long*)(cand + ((size_t)(n * KCB + k)) * 8 + hi * 4) = pk;
}

// ---------------------------------------------------------------------------
// k_merge v3 (wave-per-n): 16x the concurrency of the serial version (R5
// counters: 100.9 us at 6.3% VALUBusy / 9.8% occupancy = latency-bound).
// One wave per vector n; lanes 0..31 = (k=lane>>3, cand c=lane&7) compute
// E = np_dot128(x_k, cand_c); lanes 32..63 compute A_k = np_dot128(x_k,x_k)
// (8-way redundant, deterministic); lo lanes fetch A via one shfl.
// Selection: per-8-lane-group lexicographic (dist, idx) min via shfl_xor
// 1/2/4. All 8 candidates of an (n,k) are distinct (each half's top-4 is
// distinct; halves cover disjoint code partitions), so the lexicographic min
// is order-independent => bit-identical to the validated serial scan
// (strict < with smaller-idx tie-break). Every np-exact op tree unchanged.
// Loss/counts/perplexity finalize protocol copied verbatim.
// ---------------------------------------------------------------------------
__global__ __launch_bounds__(256) void k_merge(
    const float* __restrict__ z_e, const float* __restrict__ cb,
    const unsigned short* __restrict__ cand, const float* __restrict__ c2np,
    float* __restrict__ out_idx, int* __restrict__ counts,
    float* __restrict__ scal, int* __restrict__ ctrs) {
  const int tid = threadIdx.x;
  const int w = tid >> 6, lane = tid & 63;
  const int n = blockIdx.x * 4 + w;        // one wave per n
  const int k = (lane & 31) >> 3;          // codebook 0..3
  const int c = lane & 7;                  // candidate slot 0..7
  const int isE = (lane < 32);

  const int g = n * KCB + k;
  const int s = cand[(size_t)g * 8 + c];

  const float* xrow = z_e + (size_t)n * DDIM + k * SUBD;
  const float* vrow = isE ? (cb + (size_t)(k * SCB + s) * SUBD) : xrow;

  // Lo lanes: E(x,c). Hi lanes: A(x,x). Same validated np-exact tree.
  const float dot = np_dot128(xrow, vrow);
  const float Av = __shfl(dot, lane | 32, 64);  // lo lane l <- A from 32+l

  float bd = 1e30f;
  int bi = SCB;
  if (isE) {
    bd = fadd(fsub(Av, fmul(2.0f, dot)), c2np[k * SCB + s]);
    bi = s;
  }
  // Lexicographic min over the 8-lane candidate group (stays within group:
  // offs 1,2,4 < 8).
#pragma unroll
  for (int off = 1; off <= 4; off <<= 1) {
    const float od = __shfl_xor(bd, off, 64);
    const int oi = __shfl_xor(bi, off, 64);
    if (od < bd || (od == bd && oi < bi)) { bd = od; bi = oi; }
  }

  const int writer = isE && (c == 0);
  if (writer) {
    out_idx[g] = (float)bi;
    atomicAdd(&counts[k * SCB + bi], 1);
  }

  // Loss partial: one bd per (n,k) -> 4 contributions per wave.
  float local = writer ? bd : 0.0f;
#pragma unroll
  for (int off = 32; off > 0; off >>= 1) local += __shfl_down(local, off, 64);
  __shared__ float red[4];
  if (lane == 0) red[w] = local;
  __syncthreads();   // also drains this block's counts atomics

  __shared__ int lastf;
  if (tid == 0) {
    atomicAdd(&scal[0], (red[0] + red[1]) + (red[2] + red[3]));
    __threadfence();
    lastf = (atomicAdd(&ctrs[0], 1) == (int)gridDim.x - 1);
  }
  __syncthreads();

  if (lastf) {
    double h = 0.0;
    for (int i = 0; i < SCB / 64; ++i) {
      const int cnt = __hip_atomic_load(&counts[w * SCB + i * 64 + lane],
                                        __ATOMIC_RELAXED, __HIP_MEMORY_SCOPE_AGENT);
      if (cnt > 0) {
        const double p = (double)cnt * (1.0 / 32768.0);
        h += p * log(p);
      }
    }
#pragma unroll
    for (int off = 32; off > 0; off >>= 1) h += __shfl_down(h, off, 64);
    __shared__ double hs[4];
    if (lane == 0) hs[w] = h;
    __syncthreads();
    if (tid == 0) {
      double perp = 0.0;
      for (int w2 = 0; w2 < 4; ++w2) perp += exp(-hs[w2]);
      scal[2] = (float)(perp * 0.25);
      const float L = __hip_atomic_load(&scal[0], __ATOMIC_RELAXED,
                                        __HIP_MEMORY_SCOPE_AGENT);
      const float m = L * (1.0f / 16777216.0f);
      scal[0] = m;   // codebook_loss
      scal[1] = m;   // commit_loss
    }
  }
}

// ---------------------------------------------------------------------------
// k_gather: coalesced gather of z_q into both output slots.
// ---------------------------------------------------------------------------
__global__ __launch_bounds__(256) void k_gather(
    const float* __restrict__ cb, const float* __restrict__ idxf,
    float* __restrict__ zq_st, float* __restrict__ zq_all) {
  const int base = blockIdx.x * 4096;
#pragma unroll
  for (int i = 0; i < 16; ++i) {
    const int q = base + i * 256 + threadIdx.x;
    const int nn = q >> 7;
    const int rem = q & 127;
    const int kk = rem >> 5;
    const int j4 = rem & 31;
    const int idx = (int)idxf[nn * KCB + kk];
    const float4 v = ((const float4*)cb)[(size_t)(kk * SCB + idx) * 32 + j4];
    ((float4*)zq_st)[q] = v;
    ((float4*)zq_all)[q] = v;
  }
}

extern "C" void kernel_launch(void* const* d_in, const int* in_sizes, int n_in,
                              void* d_out, int out_size, void* d_ws, size_t ws_size,
                              hipStream_t stream) {
  const float* z_e = (const float*)d_in[0];
  const float* cb = (const float*)d_in[1];
  float* out = (float*)d_out;

  float* zq_all = out + OFF_ZQ_ALL;
  int* counts = (int*)zq_all;
  float* c2s = zq_all + 4096;
  float* c2np = zq_all + 8192;
  unsigned int* cb16 = (unsigned int*)(zq_all + 12288);
  unsigned short* cand = (unsigned short*)(zq_all + 274432);
  int* ctrs = (int*)(zq_all + 800000);
  float* scal = out + OFF_SCAL;

  k_prep<<<64, 256, 0, stream>>>(cb, cb16, c2s, c2np, counts, scal, ctrs);
  dim3 gs(NVEC / 128, KCB);
  k_scan<<<gs, 256, 0, stream>>>(z_e, cb16, c2s, cand);
  k_merge<<<NVEC / 4, 256, 0, stream>>>(z_e, cb, cand, c2np, out, counts,
                                        scal, ctrs);
  k_gather<<<1024, 256, 0, stream>>>(cb, out, out + OFF_ZQ_ST, zq_all);
}

// Round 8
// 564.458 us; speedup vs baseline: 1.0015x; 1.0015x over previous
//
#include <hip/hip_runtime.h>
#include <math.h>

// Problem constants
#define NVEC  32768          // B*L = 64*512
#define DDIM  512            // CODE_DIM
#define KCB   4              // NUM_CODEBOOKS
#define SCB   1024           // CODEBOOK_SIZE
#define SUBD  128            // SUB_DIM

#define IDX_COUNT (NVEC * KCB)            // 131072
#define ZQ_COUNT  (NVEC * DDIM)           // 16777216
#define OFF_ZQ_ST  IDX_COUNT
#define OFF_ZQ_ALL (IDX_COUNT + ZQ_COUNT)
#define OFF_SCAL   (IDX_COUNT + 2 * ZQ_COUNT)

// Scratch layout inside the z_q_all output region (all consumed before
// k_gather overwrites it; d_ws unused):
//   counts : int  [4096]               at zq_all + 0       (floats)
//   c2s    : f32  [4096] (scaled 2^20) at zq_all + 4096
//   c2np   : f32  [4096] (np-exact)    at zq_all + 8192
//   cb16   : fp16 [4096][128] (x1024)  at zq_all + 12288   (1 MB, ends 274432)
//   cand   : u16  [131072][8]          at zq_all + 274432  (2 MB, ends 798720)
//   ctrs   : int  [2]                  at zq_all + 800000

typedef _Float16 v2h __attribute__((ext_vector_type(2)));
typedef _Float16 f16x8 __attribute__((ext_vector_type(8)));
typedef float f32x16 __attribute__((ext_vector_type(16)));
union U32H2 { unsigned int u; v2h h; };

// Strict (non-contractable) f32 ops replicating numpy's rounding exactly.
__device__ __forceinline__ float fmul(float a, float b) { return __fmul_rn(a, b); }
__device__ __forceinline__ float fadd(float a, float b) { return __fadd_rn(a, b); }
__device__ __forceinline__ float fsub(float a, float b) { return __fsub_rn(a, b); }

// numpy pairwise_sum for n=128 (scalar 8-accumulator path); elements are
// individually-rounded f32 products. Validated (PASS since round 4).
__device__ __forceinline__ float np_dot128(const float* __restrict__ u,
                                           const float* __restrict__ v) {
  float r[8];
#pragma unroll
  for (int j = 0; j < 8; ++j) r[j] = fmul(u[j], v[j]);
#pragma unroll
  for (int i = 8; i < 128; i += 8) {
#pragma unroll
    for (int j = 0; j < 8; ++j) r[j] = fadd(r[j], fmul(u[i + j], v[i + j]));
  }
  return fadd(fadd(fadd(r[0], r[1]), fadd(r[2], r[3])),
              fadd(fadd(r[4], r[5]), fadd(r[6], r[7])));
}

// Same op tree as np_dot128 (element j of chunk i: j=0..3 -> ua.xyzw,
// j=4..7 -> ub.xyzw), but with explicit float4 loads: 64 vector loads per
// lane instead of 256 scalar dword loads. Arithmetic is bit-identical.
__device__ __forceinline__ float np_dot128_f4(const float4* __restrict__ u,
                                              const float4* __restrict__ v) {
  float r[8];
  {
    const float4 ua = u[0], ub = u[1], va = v[0], vb = v[1];
    r[0] = fmul(ua.x, va.x); r[1] = fmul(ua.y, va.y);
    r[2] = fmul(ua.z, va.z); r[3] = fmul(ua.w, va.w);
    r[4] = fmul(ub.x, vb.x); r[5] = fmul(ub.y, vb.y);
    r[6] = fmul(ub.z, vb.z); r[7] = fmul(ub.w, vb.w);
  }
#pragma unroll
  for (int i = 1; i < 16; ++i) {
    const float4 ua = u[2 * i], ub = u[2 * i + 1];
    const float4 va = v[2 * i], vb = v[2 * i + 1];
    r[0] = fadd(r[0], fmul(ua.x, va.x)); r[1] = fadd(r[1], fmul(ua.y, va.y));
    r[2] = fadd(r[2], fmul(ua.z, va.z)); r[3] = fadd(r[3], fmul(ua.w, va.w));
    r[4] = fadd(r[4], fmul(ub.x, vb.x)); r[5] = fadd(r[5], fmul(ub.y, vb.y));
    r[6] = fadd(r[6], fmul(ub.z, vb.z)); r[7] = fadd(r[7], fmul(ub.w, vb.w));
  }
  return fadd(fadd(fadd(r[0], r[1]), fadd(r[2], r[3])),
              fadd(fadd(r[4], r[5]), fadd(r[6], r[7])));
}

__device__ __forceinline__ int imin(int a, int b) { return a < b ? a : b; }
__device__ __forceinline__ int imax(int a, int b) { return a > b ? a : b; }

// Branch-free sorted insert of x into ascending (k0<=k1<=k2<=k3): 7 VALU ops.
__device__ __forceinline__ void ins4(int& k0, int& k1, int& k2, int& k3, int x) {
  int a = imax(k0, x); k0 = imin(k0, x);
  int b = imax(k1, a); k1 = imin(k1, a);
  int c = imax(k2, b); k2 = imin(k2, b);
  k3 = imin(k3, c);
}

// ---------------------------------------------------------------------------
// k_prep: fused convert + c2np + all zero-init. Grid 64x256.
// ---------------------------------------------------------------------------
__global__ __launch_bounds__(256) void k_prep(
    const float* __restrict__ cb, unsigned int* __restrict__ cb16,
    float* __restrict__ c2s, float* __restrict__ c2np,
    int* __restrict__ counts, float* __restrict__ scal,
    int* __restrict__ ctrs) {
  const int gt = blockIdx.x * 256 + threadIdx.x;   // 0..16383
  if (gt < KCB * SCB) counts[gt] = 0;
  if (gt < 3) scal[gt] = 0.0f;
  if (gt < 2) ctrs[gt] = 0;
  if (gt < KCB * SCB) {
    const float* row = cb + (size_t)gt * SUBD;
    c2np[gt] = np_dot128(row, row);
  }
  const int wave = blockIdx.x * 4 + (threadIdx.x >> 6);
  const int lane = threadIdx.x & 63;
  for (int i = 0; i < 16; ++i) {
    const int code = wave * 16 + i;   // 0..4095
    const float2 v = ((const float2*)(cb + (size_t)code * SUBD))[lane];
    float tot = fmaf(v.x, v.x, v.y * v.y);
#pragma unroll
    for (int off = 32; off > 0; off >>= 1) tot += __shfl_down(tot, off, 64);
    v2h h; h.x = (_Float16)(v.x * 1024.0f); h.y = (_Float16)(v.y * 1024.0f);
    U32H2 t; t.h = h;
    cb16[(size_t)code * 64 + lane] = t.u;
    if (lane == 0) c2s[code] = tot * 1048576.0f;  // * 2^20
  }
}

// ---------------------------------------------------------------------------
// k_scan: byte-identical to the PASSING round-5 kernel (MFMA + packed-key
// top-4 + global_load_lds width=16 async staging).
// ---------------------------------------------------------------------------
#define SCORE(ACC, STOFF, K0, K1, K2, K3)                                    \
  {                                                                          \
    _Pragma("unroll")                                                        \
    for (int g = 0; g < 4; ++g) {                                            \
      const float4 cv = *(const float4*)(c2b + (STOFF) + hi * 4 + g * 8);    \
      const float ca[4] = {cv.x, cv.y, cv.z, cv.w};                          \
      _Pragma("unroll")                                                      \
      for (int r = 0; r < 4; ++r) {                                          \
        const float sc = fmaf(-2048.0f, (ACC)[g * 4 + r], ca[r]);            \
        const int key = ((int)sc << 10) | (tb + (STOFF) + hi * 4 + g * 8 + r); \
        ins4(K0, K1, K2, K3, key);                                           \
      }                                                                      \
    }                                                                        \
  }

// One 16 KB tile: per wave w, chunk p covers uint4 slots [p*256+w*64,
// p*256+w*64+64). Lane l supplies the 16B at global index
// (p*16 + rbase)*16 + ss (pre-swizzled source).
__device__ __forceinline__ void stage_tile(const uint4* __restrict__ gsrc,
                                           unsigned int* lds_u32,
                                           int w, int rbase, int ss) {
#pragma unroll
  for (int p = 0; p < 4; ++p) {
    const uint4* src = gsrc + (size_t)((p * 16 + rbase) * 16 + ss);
    unsigned int* dst = lds_u32 + (p * 256 + w * 64) * 4;  // wave-uniform
    __builtin_amdgcn_global_load_lds(
        (const __attribute__((address_space(1))) unsigned int*)src,
        (__attribute__((address_space(3))) unsigned int*)dst, 16, 0, 0);
  }
}

__global__ __launch_bounds__(256) void k_scan(
    const float* __restrict__ z_e, const unsigned int* __restrict__ cb16,
    const float* __restrict__ c2s, unsigned short* __restrict__ cand) {
  const int tid = threadIdx.x;
  const int lane = tid & 63;
  const int w = tid >> 6;
  const int hi = lane >> 5;          // row-half of the lane pair
  const int ml = lane & 31;          // n-column within the wave tile
  const int k = blockIdx.y;
  const int n = blockIdx.x * 128 + w * 32 + ml;

  __shared__ __align__(16) unsigned int ctile[2][4096];  // 2 x 16 KB (64 codes)

  const uint4* gk = (const uint4*)cb16 + (size_t)k * SCB * 16;
  const float* c2k = c2s + k * SCB;
  const int rbase = tid >> 4;                 // staging row low bits
  const int ss = (tid & 15) ^ rbase;          // pre-swizzled source slot

  // B fragments: xf[ks][j] = f16(x[n][ks*16 + hi*8 + j])  (RTNE, unscaled)
  f16x8 xf[8];
  {
    const float* xp = z_e + (size_t)n * DDIM + k * SUBD + hi * 8;
#pragma unroll
    for (int ks = 0; ks < 8; ++ks) {
      const float4 a = *(const float4*)(xp + ks * 16);
      const float4 b = *(const float4*)(xp + ks * 16 + 4);
      f16x8 h;
      h[0] = (_Float16)a.x; h[1] = (_Float16)a.y;
      h[2] = (_Float16)a.z; h[3] = (_Float16)a.w;
      h[4] = (_Float16)b.x; h[5] = (_Float16)b.y;
      h[6] = (_Float16)b.z; h[7] = (_Float16)b.w;
      xf[ks] = h;
    }
  }

  // Stage tile 0 (async), then barrier (drains vmcnt).
  stage_tile(gk, ctile[0], w, rbase, ss);
  __syncthreads();

  int kA0 = 0x7FFFFFFF, kA1 = 0x7FFFFFFF, kA2 = 0x7FFFFFFF, kA3 = 0x7FFFFFFF;
  int kB0 = 0x7FFFFFFF, kB1 = 0x7FFFFFFF, kB2 = 0x7FFFFFFF, kB3 = 0x7FFFFFFF;

  for (int tile = 0; tile < 16; ++tile) {
    // Async-stage next tile into the other buffer; in flight during compute,
    // drained by the vmcnt(0) the compiler emits before the end-of-loop
    // barrier.
    if (tile < 15)
      stage_tile(gk + (size_t)(tile + 1) * 1024, ctile[(tile + 1) & 1],
                 w, rbase, ss);

    const unsigned char* bufb = (const unsigned char*)ctile[tile & 1];
    f32x16 acc0, acc1;
#pragma unroll
    for (int z = 0; z < 16; ++z) { acc0[z] = 0.0f; acc1[z] = 0.0f; }

    // Two independent 32-code MFMA chains. A-frag: row = stile*32 + ml,
    // logical 16B slot = ks*2 + hi, phys slot = slot ^ (lane&15).
#pragma unroll
    for (int ks = 0; ks < 8; ++ks) {
      const int phys = (((ks * 2 + hi) ^ (lane & 15)) << 4);
      const f16x8 a0 = *(const f16x8*)(bufb + ml * 256 + phys);
      const f16x8 a1 = *(const f16x8*)(bufb + (ml + 32) * 256 + phys);
      acc0 = __builtin_amdgcn_mfma_f32_32x32x16_f16(a0, xf[ks], acc0, 0, 0, 0);
      acc1 = __builtin_amdgcn_mfma_f32_32x32x16_f16(a1, xf[ks], acc1, 0, 0, 0);
    }

    // Scores: acc reg -> code row = (reg&3) + 8*(reg>>2) + 4*hi (m74/m101).
    const int tb = tile * 64;
    const float* c2b = c2k + tb;
    SCORE(acc0, 0, kA0, kA1, kA2, kA3)
    SCORE(acc1, 32, kB0, kB1, kB2, kB3)

    __syncthreads();
  }

  // Merge set B into set A -> top-4 of this lane's 512-code partition.
  ins4(kA0, kA1, kA2, kA3, kB0);
  ins4(kA0, kA1, kA2, kA3, kB1);
  ins4(kA0, kA1, kA2, kA3, kB2);
  ins4(kA0, kA1, kA2, kA3, kB3);

  const unsigned long long pk =
      (unsigned long long)(unsigned short)(kA0 & 1023) |
      ((unsigned long long)(unsigned short)(kA1 & 1023) << 16) |
      ((unsigned long long)(unsigned short)(kA2 & 1023) << 32) |
      ((unsigned long long)(unsigned short)(kA3 & 1023) << 48);
  *(unsigned long long*)(cand + ((size_t)(n * KCB + k)) * 8 + hi * 4) = pk;
}

// ---------------------------------------------------------------------------
// k_merge v4: identical wave-per-n structure and selection to the PASSING
// round-7 kernel; the ONLY change is the dot loop — np_dot128_f4 replaces the
// scalar-pointer np_dot128 (same op tree, float4 loads). R7 counters showed
// the scalar version was L1-thrash/L2-traffic-bound: 256 uncoalesced scalar
// loads/lane, VALUBusy 4.1%, VGPR 32, 315 us despite 80% occupancy.
// ---------------------------------------------------------------------------
__global__ __launch_bounds__(256) void k_merge(
    const float* __restrict__ z_e, const float* __restrict__ cb,
    const unsigned short* __restrict__ cand, const float* __restrict__ c2np,
    float* __restrict__ out_idx, int* __restrict__ counts,
    float* __restrict__ scal, int* __restrict__ ctrs) {
  const int tid = threadIdx.x;
  const int w = tid >> 6, lane = tid & 63;
  const int n = blockIdx.x * 4 + w;        // one wave per n
  const int k = (lane & 31) >> 3;          // codebook 0..3
  const int c = lane & 7;                  // candidate slot 0..7
  const int isE = (lane < 32);

  const int g = n * KCB + k;
  const int s = cand[(size_t)g * 8 + c];

  const float* xrow = z_e + (size_t)n * DDIM + k * SUBD;
  const float* vrow = isE ? (cb + (size_t)(k * SCB + s) * SUBD) : xrow;

  // Lo lanes: E(x,c). Hi lanes: A(x,x). Same validated np-exact tree,
  // float4 loads.
  const float dot = np_dot128_f4((const float4*)xrow, (const float4*)vrow);
  const float Av = __shfl(dot, lane | 32, 64);  // lo lane l <- A from 32+l

  float bd = 1e30f;
  int bi = SCB;
  if (isE) {
    bd = fadd(fsub(Av, fmul(2.0f, dot)), c2np[k * SCB + s]);
    bi = s;
  }
  // Lexicographic min over the 8-lane candidate group (stays within group:
  // offs 1,2,4 < 8).
#pragma unroll
  for (int off = 1; off <= 4; off <<= 1) {
    const float od = __shfl_xor(bd, off, 64);
    const int oi = __shfl_xor(bi, off, 64);
    if (od < bd || (od == bd && oi < bi)) { bd = od; bi = oi; }
  }

  const int writer = isE && (c == 0);
  if (writer) {
    out_idx[g] = (float)bi;
    atomicAdd(&counts[k * SCB + bi], 1);
  }

  // Loss partial: one bd per (n,k) -> 4 contributions per wave.
  float local = writer ? bd : 0.0f;
#pragma unroll
  for (int off = 32; off > 0; off >>= 1) local += __shfl_down(local, off, 64);
  __shared__ float red[4];
  if (lane == 0) red[w] = local;
  __syncthreads();   // also drains this block's counts atomics

  __shared__ int lastf;
  if (tid == 0) {
    atomicAdd(&scal[0], (red[0] + red[1]) + (red[2] + red[3]));
    __threadfence();
    lastf = (atomicAdd(&ctrs[0], 1) == (int)gridDim.x - 1);
  }
  __syncthreads();

  if (lastf) {
    double h = 0.0;
    for (int i = 0; i < SCB / 64; ++i) {
      const int cnt = __hip_atomic_load(&counts[w * SCB + i * 64 + lane],
                                        __ATOMIC_RELAXED, __HIP_MEMORY_SCOPE_AGENT);
      if (cnt > 0) {
        const double p = (double)cnt * (1.0 / 32768.0);
        h += p * log(p);
      }
    }
#pragma unroll
    for (int off = 32; off > 0; off >>= 1) h += __shfl_down(h, off, 64);
    __shared__ double hs[4];
    if (lane == 0) hs[w] = h;
    __syncthreads();
    if (tid == 0) {
      double perp = 0.0;
      for (int w2 = 0; w2 < 4; ++w2) perp += exp(-hs[w2]);
      scal[2] = (float)(perp * 0.25);
      const float L = __hip_atomic_load(&scal[0], __ATOMIC_RELAXED,
                                        __HIP_MEMORY_SCOPE_AGENT);
      const float m = L * (1.0f / 16777216.0f);
      scal[0] = m;   // codebook_loss
      scal[1] = m;   // commit_loss
    }
  }
}

// ---------------------------------------------------------------------------
// k_gather: coalesced gather of z_q into both output slots.
// ---------------------------------------------------------------------------
__global__ __launch_bounds__(256) void k_gather(
    const float* __restrict__ cb, const float* __restrict__ idxf,
    float* __restrict__ zq_st, float* __restrict__ zq_all) {
  const int base = blockIdx.x * 4096;
#pragma unroll
  for (int i = 0; i < 16; ++i) {
    const int q = base + i * 256 + threadIdx.x;
    const int nn = q >> 7;
    const int rem = q & 127;
    const int kk = rem >> 5;
    const int j4 = rem & 31;
    const int idx = (int)idxf[nn * KCB + kk];
    const float4 v = ((const float4*)cb)[(size_t)(kk * SCB + idx) * 32 + j4];
    ((float4*)zq_st)[q] = v;
    ((float4*)zq_all)[q] = v;
  }
}

extern "C" void kernel_launch(void* const* d_in, const int* in_sizes, int n_in,
                              void* d_out, int out_size, void* d_ws, size_t ws_size,
                              hipStream_t stream) {
  const float* z_e = (const float*)d_in[0];
  const float* cb = (const float*)d_in[1];
  float* out = (float*)d_out;

  float* zq_all = out + OFF_ZQ_ALL;
  int* counts = (int*)zq_all;
  float* c2s = zq_all + 4096;
  float* c2np = zq_all + 8192;
  unsigned int* cb16 = (unsigned int*)(zq_all + 12288);
  unsigned short* cand = (unsigned short*)(zq_all + 274432);
  int* ctrs = (int*)(zq_all + 800000);
  float* scal = out + OFF_SCAL;

  k_prep<<<64, 256, 0, stream>>>(cb, cb16, c2s, c2np, counts, scal, ctrs);
  dim3 gs(NVEC / 128, KCB);
  k_scan<<<gs, 256, 0, stream>>>(z_e, cb16, c2s, cand);
  k_merge<<<NVEC / 4, 256, 0, stream>>>(z_e, cb, cand, c2np, out, counts,
                                        scal, ctrs);
  k_gather<<<1024, 256, 0, stream>>>(cb, out, out + OFF_ZQ_ST, zq_all);
}

// Round 9
// 561.193 us; speedup vs baseline: 1.0073x; 1.0058x over previous
//
#include <hip/hip_runtime.h>
#include <math.h>

// Problem constants
#define NVEC  32768          // B*L = 64*512
#define DDIM  512            // CODE_DIM
#define KCB   4              // NUM_CODEBOOKS
#define SCB   1024           // CODEBOOK_SIZE
#define SUBD  128            // SUB_DIM

#define IDX_COUNT (NVEC * KCB)            // 131072
#define ZQ_COUNT  (NVEC * DDIM)           // 16777216
#define OFF_ZQ_ST  IDX_COUNT
#define OFF_ZQ_ALL (IDX_COUNT + ZQ_COUNT)
#define OFF_SCAL   (IDX_COUNT + 2 * ZQ_COUNT)

// Scratch layout inside the z_q_all output region (all consumed before
// k_gather overwrites it; d_ws unused):
//   counts : int  [4096]               at zq_all + 0       (floats)
//   c2s    : f32  [4096] (scaled 2^20) at zq_all + 4096
//   c2np   : f32  [4096] (np-exact)    at zq_all + 8192
//   cb16   : fp16 [4096][128] (x1024)  at zq_all + 12288   (1 MB, ends 274432)
//   cand   : u16  [131072][8]          at zq_all + 274432  (2 MB, ends 798720)
//   ctrs   : int  [2]                  at zq_all + 800000

typedef _Float16 v2h __attribute__((ext_vector_type(2)));
typedef _Float16 f16x8 __attribute__((ext_vector_type(8)));
typedef float f32x16 __attribute__((ext_vector_type(16)));
union U32H2 { unsigned int u; v2h h; };

// Strict (non-contractable) f32 ops replicating numpy's rounding exactly.
__device__ __forceinline__ float fmul(float a, float b) { return __fmul_rn(a, b); }
__device__ __forceinline__ float fadd(float a, float b) { return __fadd_rn(a, b); }
__device__ __forceinline__ float fsub(float a, float b) { return __fsub_rn(a, b); }

// numpy pairwise_sum for n=128 (scalar 8-accumulator path); elements are
// individually-rounded f32 products. Validated (PASS since round 4).
__device__ __forceinline__ float np_dot128(const float* __restrict__ u,
                                           const float* __restrict__ v) {
  float r[8];
#pragma unroll
  for (int j = 0; j < 8; ++j) r[j] = fmul(u[j], v[j]);
#pragma unroll
  for (int i = 8; i < 128; i += 8) {
#pragma unroll
    for (int j = 0; j < 8; ++j) r[j] = fadd(r[j], fmul(u[i + j], v[i + j]));
  }
  return fadd(fadd(fadd(r[0], r[1]), fadd(r[2], r[3])),
              fadd(fadd(r[4], r[5]), fadd(r[6], r[7])));
}

__device__ __forceinline__ int imin(int a, int b) { return a < b ? a : b; }
__device__ __forceinline__ int imax(int a, int b) { return a > b ? a : b; }

// Branch-free sorted insert of x into ascending (k0<=k1<=k2<=k3): 7 VALU ops.
__device__ __forceinline__ void ins4(int& k0, int& k1, int& k2, int& k3, int x) {
  int a = imax(k0, x); k0 = imin(k0, x);
  int b = imax(k1, a); k1 = imin(k1, a);
  int c = imax(k2, b); k2 = imin(k2, b);
  k3 = imin(k3, c);
}

// ---------------------------------------------------------------------------
// k_prep: fused convert + c2np + all zero-init. Grid 64x256.
// ---------------------------------------------------------------------------
__global__ __launch_bounds__(256) void k_prep(
    const float* __restrict__ cb, unsigned int* __restrict__ cb16,
    float* __restrict__ c2s, float* __restrict__ c2np,
    int* __restrict__ counts, float* __restrict__ scal,
    int* __restrict__ ctrs) {
  const int gt = blockIdx.x * 256 + threadIdx.x;   // 0..16383
  if (gt < KCB * SCB) counts[gt] = 0;
  if (gt < 3) scal[gt] = 0.0f;
  if (gt < 2) ctrs[gt] = 0;
  if (gt < KCB * SCB) {
    const float* row = cb + (size_t)gt * SUBD;
    c2np[gt] = np_dot128(row, row);
  }
  const int wave = blockIdx.x * 4 + (threadIdx.x >> 6);
  const int lane = threadIdx.x & 63;
  for (int i = 0; i < 16; ++i) {
    const int code = wave * 16 + i;   // 0..4095
    const float2 v = ((const float2*)(cb + (size_t)code * SUBD))[lane];
    float tot = fmaf(v.x, v.x, v.y * v.y);
#pragma unroll
    for (int off = 32; off > 0; off >>= 1) tot += __shfl_down(tot, off, 64);
    v2h h; h.x = (_Float16)(v.x * 1024.0f); h.y = (_Float16)(v.y * 1024.0f);
    U32H2 t; t.h = h;
    cb16[(size_t)code * 64 + lane] = t.u;
    if (lane == 0) c2s[code] = tot * 1048576.0f;  // * 2^20
  }
}

// ---------------------------------------------------------------------------
// k_scan: byte-identical to the PASSING round-5 kernel (MFMA + packed-key
// top-4 + global_load_lds width=16 async staging).
// ---------------------------------------------------------------------------
#define SCORE(ACC, STOFF, K0, K1, K2, K3)                                    \
  {                                                                          \
    _Pragma("unroll")                                                        \
    for (int g = 0; g < 4; ++g) {                                            \
      const float4 cv = *(const float4*)(c2b + (STOFF) + hi * 4 + g * 8);    \
      const float ca[4] = {cv.x, cv.y, cv.z, cv.w};                          \
      _Pragma("unroll")                                                      \
      for (int r = 0; r < 4; ++r) {                                          \
        const float sc = fmaf(-2048.0f, (ACC)[g * 4 + r], ca[r]);            \
        const int key = ((int)sc << 10) | (tb + (STOFF) + hi * 4 + g * 8 + r); \
        ins4(K0, K1, K2, K3, key);                                           \
      }                                                                      \
    }                                                                        \
  }

// One 16 KB tile: per wave w, chunk p covers uint4 slots [p*256+w*64,
// p*256+w*64+64). Lane l supplies the 16B at global index
// (p*16 + rbase)*16 + ss (pre-swizzled source).
__device__ __forceinline__ void stage_tile(const uint4* __restrict__ gsrc,
                                           unsigned int* lds_u32,
                                           int w, int rbase, int ss) {
#pragma unroll
  for (int p = 0; p < 4; ++p) {
    const uint4* src = gsrc + (size_t)((p * 16 + rbase) * 16 + ss);
    unsigned int* dst = lds_u32 + (p * 256 + w * 64) * 4;  // wave-uniform
    __builtin_amdgcn_global_load_lds(
        (const __attribute__((address_space(1))) unsigned int*)src,
        (__attribute__((address_space(3))) unsigned int*)dst, 16, 0, 0);
  }
}

__global__ __launch_bounds__(256) void k_scan(
    const float* __restrict__ z_e, const unsigned int* __restrict__ cb16,
    const float* __restrict__ c2s, unsigned short* __restrict__ cand) {
  const int tid = threadIdx.x;
  const int lane = tid & 63;
  const int w = tid >> 6;
  const int hi = lane >> 5;          // row-half of the lane pair
  const int ml = lane & 31;          // n-column within the wave tile
  const int k = blockIdx.y;
  const int n = blockIdx.x * 128 + w * 32 + ml;

  __shared__ __align__(16) unsigned int ctile[2][4096];  // 2 x 16 KB (64 codes)

  const uint4* gk = (const uint4*)cb16 + (size_t)k * SCB * 16;
  const float* c2k = c2s + k * SCB;
  const int rbase = tid >> 4;                 // staging row low bits
  const int ss = (tid & 15) ^ rbase;          // pre-swizzled source slot

  // B fragments: xf[ks][j] = f16(x[n][ks*16 + hi*8 + j])  (RTNE, unscaled)
  f16x8 xf[8];
  {
    const float* xp = z_e + (size_t)n * DDIM + k * SUBD + hi * 8;
#pragma unroll
    for (int ks = 0; ks < 8; ++ks) {
      const float4 a = *(const float4*)(xp + ks * 16);
      const float4 b = *(const float4*)(xp + ks * 16 + 4);
      f16x8 h;
      h[0] = (_Float16)a.x; h[1] = (_Float16)a.y;
      h[2] = (_Float16)a.z; h[3] = (_Float16)a.w;
      h[4] = (_Float16)b.x; h[5] = (_Float16)b.y;
      h[6] = (_Float16)b.z; h[7] = (_Float16)b.w;
      xf[ks] = h;
    }
  }

  // Stage tile 0 (async), then barrier (drains vmcnt).
  stage_tile(gk, ctile[0], w, rbase, ss);
  __syncthreads();

  int kA0 = 0x7FFFFFFF, kA1 = 0x7FFFFFFF, kA2 = 0x7FFFFFFF, kA3 = 0x7FFFFFFF;
  int kB0 = 0x7FFFFFFF, kB1 = 0x7FFFFFFF, kB2 = 0x7FFFFFFF, kB3 = 0x7FFFFFFF;

  for (int tile = 0; tile < 16; ++tile) {
    // Async-stage next tile into the other buffer; in flight during compute,
    // drained by the vmcnt(0) the compiler emits before the end-of-loop
    // barrier.
    if (tile < 15)
      stage_tile(gk + (size_t)(tile + 1) * 1024, ctile[(tile + 1) & 1],
                 w, rbase, ss);

    const unsigned char* bufb = (const unsigned char*)ctile[tile & 1];
    f32x16 acc0, acc1;
#pragma unroll
    for (int z = 0; z < 16; ++z) { acc0[z] = 0.0f; acc1[z] = 0.0f; }

    // Two independent 32-code MFMA chains. A-frag: row = stile*32 + ml,
    // logical 16B slot = ks*2 + hi, phys slot = slot ^ (lane&15).
#pragma unroll
    for (int ks = 0; ks < 8; ++ks) {
      const int phys = (((ks * 2 + hi) ^ (lane & 15)) << 4);
      const f16x8 a0 = *(const f16x8*)(bufb + ml * 256 + phys);
      const f16x8 a1 = *(const f16x8*)(bufb + (ml + 32) * 256 + phys);
      acc0 = __builtin_amdgcn_mfma_f32_32x32x16_f16(a0, xf[ks], acc0, 0, 0, 0);
      acc1 = __builtin_amdgcn_mfma_f32_32x32x16_f16(a1, xf[ks], acc1, 0, 0, 0);
    }

    // Scores: acc reg -> code row = (reg&3) + 8*(reg>>2) + 4*hi (m74/m101).
    const int tb = tile * 64;
    const float* c2b = c2k + tb;
    SCORE(acc0, 0, kA0, kA1, kA2, kA3)
    SCORE(acc1, 32, kB0, kB1, kB2, kB3)

    __syncthreads();
  }

  // Merge set B into set A -> top-4 of this lane's 512-code partition.
  ins4(kA0, kA1, kA2, kA3, kB0);
  ins4(kA0, kA1, kA2, kA3, kB1);
  ins4(kA0, kA1, kA2, kA3, kB2);
  ins4(kA0, kA1, kA2, kA3, kB3);

  const unsigned long long pk =
      (unsigned long long)(unsigned short)(kA0 & 1023) |
      ((unsigned long long)(unsigned short)(kA1 & 1023) << 16) |
      ((unsigned long long)(unsigned short)(kA2 & 1023) << 32) |
      ((unsigned long long)(unsigned short)(kA3 & 1023) << 48);
  *(unsigned long long*)(cand + ((size_t)(n * KCB + k)) * 8 + hi * 4) = pk;
}

// ---------------------------------------------------------------------------
// k_merge v5 (lane-pair split): R8 counters proved the gather is TA/L1
// transaction-bound (~36 lines per load instr, VALUBusy 4%, identical dur for
// scalar vs float4). Fix: lane pair (l, l+32) shares one (k,c) dot — lo lane
// owns np accumulators j=0..3 (even float4s of the row), hi lane j=4..7 (odd
// float4s). Pair reads adjacent 16B of the SAME row -> same 64B line: v-loads
// drop to 32 lines/instr x 16 instrs; x is loaded once per lane (serves both
// A and E; 8-lane groups broadcast-read the same x address). ~576 lines/wave
// vs ~2800. Arithmetic: each per-j chain is strictly sequential in i within
// one lane; final combine fadd(lo_part, hi_part) is exactly np_dot128's root
// fadd => bit-identical result. Selection/loss/perp protocol unchanged
// (writer lanes 0,8,16,24 per wave).
// ---------------------------------------------------------------------------
__global__ __launch_bounds__(256) void k_merge(
    const float* __restrict__ z_e, const float* __restrict__ cb,
    const unsigned short* __restrict__ cand, const float* __restrict__ c2np,
    float* __restrict__ out_idx, int* __restrict__ counts,
    float* __restrict__ scal, int* __restrict__ ctrs) {
  const int tid = threadIdx.x;
  const int w = tid >> 6, lane = tid & 63;
  const int n = blockIdx.x * 4 + w;        // one wave per n
  const int hi = lane >> 5;                // j-half: 0 -> j0..3, 1 -> j4..7
  const int k = (lane & 31) >> 3;          // codebook 0..3
  const int c = lane & 7;                  // candidate slot 0..7

  const int g = n * KCB + k;
  const int s = cand[(size_t)g * 8 + c];

  // Half-row pointers: this lane reads float4 indices {2i + hi, i=0..15}.
  const float4* xp = (const float4*)(z_e + (size_t)n * DDIM + k * SUBD) + hi;
  const float4* vp = (const float4*)(cb + (size_t)(k * SCB + s) * SUBD) + hi;

  // Stage x half-row into registers (burst of 16 independent loads).
  float4 xh[16];
#pragma unroll
  for (int i = 0; i < 16; ++i) xh[i] = xp[2 * i];

  // A partial: this half's 4 accumulators, exact per-j chain over i.
  float ra0 = fmul(xh[0].x, xh[0].x), ra1 = fmul(xh[0].y, xh[0].y);
  float ra2 = fmul(xh[0].z, xh[0].z), ra3 = fmul(xh[0].w, xh[0].w);
#pragma unroll
  for (int i = 1; i < 16; ++i) {
    ra0 = fadd(ra0, fmul(xh[i].x, xh[i].x));
    ra1 = fadd(ra1, fmul(xh[i].y, xh[i].y));
    ra2 = fadd(ra2, fmul(xh[i].z, xh[i].z));
    ra3 = fadd(ra3, fmul(xh[i].w, xh[i].w));
  }
  const float pa = fadd(fadd(ra0, ra1), fadd(ra2, ra3));

  // E partial: v streamed in two 8-float4 bursts.
  float4 vh[8];
#pragma unroll
  for (int i = 0; i < 8; ++i) vh[i] = vp[2 * i];
  float re0 = fmul(xh[0].x, vh[0].x), re1 = fmul(xh[0].y, vh[0].y);
  float re2 = fmul(xh[0].z, vh[0].z), re3 = fmul(xh[0].w, vh[0].w);
#pragma unroll
  for (int i = 1; i < 8; ++i) {
    re0 = fadd(re0, fmul(xh[i].x, vh[i].x));
    re1 = fadd(re1, fmul(xh[i].y, vh[i].y));
    re2 = fadd(re2, fmul(xh[i].z, vh[i].z));
    re3 = fadd(re3, fmul(xh[i].w, vh[i].w));
  }
#pragma unroll
  for (int i = 0; i < 8; ++i) vh[i] = vp[2 * (i + 8)];
#pragma unroll
  for (int i = 8; i < 16; ++i) {
    re0 = fadd(re0, fmul(xh[i].x, vh[i - 8].x));
    re1 = fadd(re1, fmul(xh[i].y, vh[i - 8].y));
    re2 = fadd(re2, fmul(xh[i].z, vh[i - 8].z));
    re3 = fadd(re3, fmul(xh[i].w, vh[i - 8].w));
  }
  const float pe = fadd(fadd(re0, re1), fadd(re2, re3));

  // Combine lane-pair halves: exactly np_dot128's root fadd(lo, hi).
  const float pao = __shfl_xor(pa, 32, 64);
  const float peo = __shfl_xor(pe, 32, 64);
  const float A = hi ? fadd(pao, pa) : fadd(pa, pao);
  const float E = hi ? fadd(peo, pe) : fadd(pe, peo);

  float bd = fadd(fsub(A, fmul(2.0f, E)), c2np[k * SCB + s]);
  int bi = s;
  // Lexicographic min over the 8-lane candidate group (both pair halves hold
  // identical values; offs 1,2,4 stay within the group).
#pragma unroll
  for (int off = 1; off <= 4; off <<= 1) {
    const float od = __shfl_xor(bd, off, 64);
    const int oi = __shfl_xor(bi, off, 64);
    if (od < bd || (od == bd && oi < bi)) { bd = od; bi = oi; }
  }

  const int writer = (lane < 32) && (c == 0);   // lanes 0,8,16,24
  if (writer) {
    out_idx[g] = (float)bi;
    atomicAdd(&counts[k * SCB + bi], 1);
  }

  // Loss partial: one bd per (n,k) -> 4 contributions per wave.
  float local = writer ? bd : 0.0f;
#pragma unroll
  for (int off = 32; off > 0; off >>= 1) local += __shfl_down(local, off, 64);
  __shared__ float red[4];
  if (lane == 0) red[w] = local;
  __syncthreads();   // also drains this block's counts atomics

  __shared__ int lastf;
  if (tid == 0) {
    atomicAdd(&scal[0], (red[0] + red[1]) + (red[2] + red[3]));
    __threadfence();
    lastf = (atomicAdd(&ctrs[0], 1) == (int)gridDim.x - 1);
  }
  __syncthreads();

  if (lastf) {
    double h = 0.0;
    for (int i = 0; i < SCB / 64; ++i) {
      const int cnt = __hip_atomic_load(&counts[w * SCB + i * 64 + lane],
                                        __ATOMIC_RELAXED, __HIP_MEMORY_SCOPE_AGENT);
      if (cnt > 0) {
        const double p = (double)cnt * (1.0 / 32768.0);
        h += p * log(p);
      }
    }
#pragma unroll
    for (int off = 32; off > 0; off >>= 1) h += __shfl_down(h, off, 64);
    __shared__ double hs[4];
    if (lane == 0) hs[w] = h;
    __syncthreads();
    if (tid == 0) {
      double perp = 0.0;
      for (int w2 = 0; w2 < 4; ++w2) perp += exp(-hs[w2]);
      scal[2] = (float)(perp * 0.25);
      const float L = __hip_atomic_load(&scal[0], __ATOMIC_RELAXED,
                                        __HIP_MEMORY_SCOPE_AGENT);
      const float m = L * (1.0f / 16777216.0f);
      scal[0] = m;   // codebook_loss
      scal[1] = m;   // commit_loss
    }
  }
}

// ---------------------------------------------------------------------------
// k_gather: coalesced gather of z_q into both output slots.
// ---------------------------------------------------------------------------
__global__ __launch_bounds__(256) void k_gather(
    const float* __restrict__ cb, const float* __restrict__ idxf,
    float* __restrict__ zq_st, float* __restrict__ zq_all) {
  const int base = blockIdx.x * 4096;
#pragma unroll
  for (int i = 0; i < 16; ++i) {
    const int q = base + i * 256 + threadIdx.x;
    const int nn = q >> 7;
    const int rem = q & 127;
    const int kk = rem >> 5;
    const int j4 = rem & 31;
    const int idx = (int)idxf[nn * KCB + kk];
    const float4 v = ((const float4*)cb)[(size_t)(kk * SCB + idx) * 32 + j4];
    ((float4*)zq_st)[q] = v;
    ((float4*)zq_all)[q] = v;
  }
}

extern "C" void kernel_launch(void* const* d_in, const int* in_sizes, int n_in,
                              void* d_out, int out_size, void* d_ws, size_t ws_size,
                              hipStream_t stream) {
  const float* z_e = (const float*)d_in[0];
  const float* cb = (const float*)d_in[1];
  float* out = (float*)d_out;

  float* zq_all = out + OFF_ZQ_ALL;
  int* counts = (int*)zq_all;
  float* c2s = zq_all + 4096;
  float* c2np = zq_all + 8192;
  unsigned int* cb16 = (unsigned int*)(zq_all + 12288);
  unsigned short* cand = (unsigned short*)(zq_all + 274432);
  int* ctrs = (int*)(zq_all + 800000);
  float* scal = out + OFF_SCAL;

  k_prep<<<64, 256, 0, stream>>>(cb, cb16, c2s, c2np, counts, scal, ctrs);
  dim3 gs(NVEC / 128, KCB);
  k_scan<<<gs, 256, 0, stream>>>(z_e, cb16, c2s, cand);
  k_merge<<<NVEC / 4, 256, 0, stream>>>(z_e, cb, cand, c2np, out, counts,
                                        scal, ctrs);
  k_gather<<<1024, 256, 0, stream>>>(cb, out, out + OFF_ZQ_ST, zq_all);
}